// Round 3
// baseline (902.805 us; speedup 1.0000x reference)
//
#include <hip/hip_runtime.h>

// RGCN bipartite, FP32 in/out. Round 3:
//   - transform on the SMALL side of each relation (row-scales commute with W):
//     both inc (B->A) convs now GEMM on 10000 rows BEFORE aggregating.
//   - GEMM: 4 N-tiles per wave w/ independent accumulators, 4 waves per strip.
//   - agg: 4-edge unroll (4 outstanding row gathers), fused scale+bias+relu
//     epilogue for the inc side.
//   CSR built once, reused by both layers. GEMM fp32 via 3-term bf16 MFMA split.

#define NA 50000
#define NB 10000
#define NE 300000

typedef unsigned short u16;
typedef unsigned int u32;
typedef __attribute__((ext_vector_type(8))) short short8;
typedef __attribute__((ext_vector_type(4))) float f32x4;

__device__ __forceinline__ float bf2f(u16 h){
  union { u32 u; float f; } x; x.u = ((u32)h) << 16; return x.f;
}
__device__ __forceinline__ u16 f2bf(float f){
  union { float f; u32 u; } x; x.f = f;
  u32 r = (x.u + 0x7FFFu + ((x.u >> 16) & 1u)) >> 16;   // RNE
  return (u16)r;
}

// ---------- zero int scratch ----------
__global__ void zero_ints(int* __restrict__ a, int na, int* __restrict__ b, int nb){
  int g = blockIdx.x * blockDim.x + threadIdx.x;
  int s = gridDim.x * blockDim.x;
  for (int i = g; i < na; i += s) a[i] = 0;
  for (int i = g; i < nb; i += s) b[i] = 0;
}

// ---------- degree histograms ----------
__global__ void hist_kernel(const int* __restrict__ bs, const int* __restrict__ bd,
                            const int* __restrict__ isc, const int* __restrict__ idt,
                            int* __restrict__ c_bs, int* __restrict__ c_bd,
                            int* __restrict__ c_is, int* __restrict__ c_id){
  int g = blockIdx.x * blockDim.x + threadIdx.x;
  int s = gridDim.x * blockDim.x;
  for (int e = g; e < NE; e += s){
    atomicAdd(&c_bs[bs[e]], 1);
    atomicAdd(&c_bd[bd[e]], 1);
    atomicAdd(&c_is[isc[e]], 1);
    atomicAdd(&c_id[idt[e]], 1);
  }
}

// ---------- exclusive scan: block 0 -> bel offsets (NB), block 1 -> inc (NA) ----
__global__ __launch_bounds__(1024) void scan_kernel(const int* __restrict__ c_bd,
                                                    const int* __restrict__ c_id,
                                                    int* __restrict__ off_bel,
                                                    int* __restrict__ off_inc){
  const int* cnt; int* off; int n;
  if (blockIdx.x == 0){ cnt = c_bd; off = off_bel; n = NB; }
  else                { cnt = c_id; off = off_inc; n = NA; }
  __shared__ int wsum[16];
  __shared__ int carry, chunkTot;
  int tid = threadIdx.x, lane = tid & 63, wid = tid >> 6;
  if (tid == 0) carry = 0;
  __syncthreads();
  for (int base = 0; base < n; base += 4096){
    int i0 = base + tid * 4;
    int v[4];
#pragma unroll
    for (int r = 0; r < 4; ++r){ int idx = i0 + r; v[r] = (idx < n) ? cnt[idx] : 0; }
    int s = v[0] + v[1] + v[2] + v[3];
    int x = s;
#pragma unroll
    for (int d = 1; d < 64; d <<= 1){ int t = __shfl_up(x, d, 64); if (lane >= d) x += t; }
    if (lane == 63) wsum[wid] = x;
    __syncthreads();
    if (wid == 0){
      int ws = (lane < 16) ? wsum[lane] : 0;
#pragma unroll
      for (int d = 1; d < 16; d <<= 1){ int t = __shfl_up(ws, d, 64); if (lane >= d) ws += t; }
      if (lane < 16) wsum[lane] = ws;
      if (lane == 15) chunkTot = ws;
    }
    __syncthreads();
    int waveBase = (wid == 0) ? 0 : wsum[wid - 1];
    int run = carry + waveBase + (x - s);
#pragma unroll
    for (int r = 0; r < 4; ++r){ int idx = i0 + r; if (idx < n) off[idx] = run; run += v[r]; }
    __syncthreads();
    if (tid == 0) carry += chunkTot;
    __syncthreads();
  }
  if (tid == 0) off[n] = carry;
}

// ---------- rsqrt(max(deg,1)) scales ----------
__global__ void scales_kernel(const int* __restrict__ c_bs, const int* __restrict__ c_bd,
                              const int* __restrict__ c_is, const int* __restrict__ c_id,
                              float* __restrict__ s_ob, float* __restrict__ s_ib,
                              float* __restrict__ s_oi, float* __restrict__ s_ii){
  int g = blockIdx.x * blockDim.x + threadIdx.x;
  int s = gridDim.x * blockDim.x;
  for (int i = g; i < NA; i += s){
    int a = c_bs[i]; s_ob[i] = rsqrtf((float)(a > 1 ? a : 1));
    int b = c_id[i]; s_ii[i] = rsqrtf((float)(b > 1 ? b : 1));
    if (i < NB){
      int c = c_bd[i]; s_ib[i] = rsqrtf((float)(c > 1 ? c : 1));
      int d = c_is[i]; s_oi[i] = rsqrtf((float)(d > 1 ? d : 1));
    }
  }
}

// ---------- CSR fill ----------
__global__ void fill_kernel(const int* __restrict__ bs, const int* __restrict__ bd,
                            const int* __restrict__ isc, const int* __restrict__ idt,
                            const int* __restrict__ off_bel, const int* __restrict__ off_inc,
                            int* __restrict__ cur_bel, int* __restrict__ cur_inc,
                            int* __restrict__ csr_bel, int* __restrict__ csr_inc){
  int g = blockIdx.x * blockDim.x + threadIdx.x;
  int s = gridDim.x * blockDim.x;
  for (int e = g; e < NE; e += s){
    int d0 = bd[e];
    int p0 = off_bel[d0] + atomicAdd(&cur_bel[d0], 1);
    csr_bel[p0] = bs[e];
    int d1 = idt[e];
    int p1 = off_inc[d1] + atomicAdd(&cur_inc[d1], 1);
    csr_inc[p1] = isc[e];
  }
}

// ---------- pack fp32 W into MFMA B-fragment order, hi/lo bf16 split ----------
// elem index = (kt*nT + nt)*512 + lane*8 + j ; B[k=(lane>>4)*8+j][n=lane&15]
__global__ void pack_kernel(const float* __restrict__ W1b, const float* __restrict__ W1i,
                            const float* __restrict__ W2b, const float* __restrict__ W2i,
                            u16* __restrict__ pwh, u16* __restrict__ pwl){
  int g = blockIdx.x * blockDim.x + threadIdx.x;
  int s = gridDim.x * blockDim.x;
  const int total = 65536 + 65536 + 32768 + 32768;
  for (int t = g; t < total; t += s){
    const float* W; int N; int tt;
    if (t < 65536)       { W = W1b; N = 256; tt = t; }
    else if (t < 131072) { W = W1i; N = 256; tt = t - 65536; }
    else if (t < 163840) { W = W2b; N = 128; tt = t - 131072; }
    else                 { W = W2i; N = 128; tt = t - 163840; }
    int j = tt & 7, lane = (tt >> 3) & 63, tile = tt >> 9;
    int nT = N >> 4;
    int nt = tile % nT, kt = tile / nT;
    int k = kt * 32 + ((lane >> 4) << 3) + j;
    int n = nt * 16 + (lane & 15);
    float v = W[k * N + n];
    u16 hi = f2bf(v);
    pwh[t] = hi;
    pwl[t] = f2bf(v - bf2f(hi));
  }
}

// ---------- aggregation: P[dst] = epi( sum_{e->dst} X[src]*(ss?ss[src]:1) ) ----------
// one wave per dst row; lane owns COLS of the F=COLS*64 columns; 4-edge unroll.
// epilogue: r = r*(rs?rs[row]:1) + (bias?bias[col]:0); optional relu.
template<int COLS>
__global__ __launch_bounds__(256) void agg_kernel(const float* __restrict__ X,
                                                  const float* __restrict__ ss,
                                                  const int* __restrict__ off,
                                                  const int* __restrict__ csr,
                                                  float* __restrict__ P, int nDst,
                                                  const float* __restrict__ rs,
                                                  const float* __restrict__ bias,
                                                  int doRelu){
  typedef __attribute__((ext_vector_type(COLS))) float vec;
  const int F = COLS * 64;
  int wave = blockIdx.x * 4 + (threadIdx.x >> 6);
  int lane = threadIdx.x & 63;
  if (wave >= nDst) return;
  int b0 = off[wave], b1 = off[wave + 1];
  int c = lane * COLS;
  vec acc0 = (vec)0.f, acc1 = (vec)0.f;
  int j = b0;
  for (; j + 3 < b1; j += 4){
    int s0 = csr[j], s1 = csr[j + 1], s2 = csr[j + 2], s3 = csr[j + 3];
    float c0 = ss ? ss[s0] : 1.f, c1 = ss ? ss[s1] : 1.f;
    float c2 = ss ? ss[s2] : 1.f, c3 = ss ? ss[s3] : 1.f;
    vec v0 = *(const vec*)(X + (size_t)s0 * F + c);
    vec v1 = *(const vec*)(X + (size_t)s1 * F + c);
    vec v2 = *(const vec*)(X + (size_t)s2 * F + c);
    vec v3 = *(const vec*)(X + (size_t)s3 * F + c);
    acc0 += v0 * c0; acc1 += v1 * c1; acc0 += v2 * c2; acc1 += v3 * c3;
  }
  for (; j < b1; ++j){
    int s0 = csr[j];
    float c0 = ss ? ss[s0] : 1.f;
    vec v0 = *(const vec*)(X + (size_t)s0 * F + c);
    acc0 += v0 * c0;
  }
  vec r = acc0 + acc1;
  float rv = rs ? rs[wave] : 1.f;
  vec bv = bias ? *(const vec*)(bias + c) : (vec)0.f;
#pragma unroll
  for (int t = 0; t < COLS; ++t){
    float v = r[t] * rv + bv[t];
    if (doRelu) v = fmaxf(v, 0.f);
    r[t] = v;
  }
  *(vec*)(P + (size_t)wave * F + c) = r;
}

// ---------- GEMM: C[M,N] = relu?( (A[M,256] @ W) * rs[m] + bias[n] ) ----------
// fp32 via 3-term bf16 split MFMA. Strip = 16 rows. wps waves per strip,
// each wave owns 4 N-tiles (independent accumulators, no MFMA dep chains).
__global__ __launch_bounds__(256) void gemm_kernel(const float* __restrict__ A,
                                                   const u16* __restrict__ PWH,
                                                   const u16* __restrict__ PWL,
                                                   const float* __restrict__ bias,
                                                   const float* __restrict__ rs,
                                                   float* __restrict__ C,
                                                   int M, int nT, int wpsShift,
                                                   int doRelu){
  int wave = blockIdx.x * 4 + (threadIdx.x >> 6);
  int lane = threadIdx.x & 63;
  int strips = M >> 4;
  int strip = wave >> wpsShift;
  if (strip >= strips) return;
  int widx = wave & ((1 << wpsShift) - 1);
  int nt0 = widx * 4;
  int N = nT << 4;
  int r16 = lane & 15, quad = lane >> 4;
  const float* aBase = A + (size_t)((strip << 4) + r16) * 256 + quad * 8;
  short8 ah[8], al[8];
#pragma unroll
  for (int kt = 0; kt < 8; ++kt){
    float4 p0 = *(const float4*)(aBase + kt * 32);
    float4 p1 = *(const float4*)(aBase + kt * 32 + 4);
    float v[8] = {p0.x, p0.y, p0.z, p0.w, p1.x, p1.y, p1.z, p1.w};
    short8 h, l;
#pragma unroll
    for (int j = 0; j < 8; ++j){
      u16 hb = f2bf(v[j]);
      h[j] = (short)hb;
      l[j] = (short)f2bf(v[j] - bf2f(hb));
    }
    ah[kt] = h; al[kt] = l;
  }
  f32x4 acc[4];
#pragma unroll
  for (int i = 0; i < 4; ++i) acc[i] = (f32x4){0.f, 0.f, 0.f, 0.f};
  for (int kt = 0; kt < 8; ++kt){
#pragma unroll
    for (int i = 0; i < 4; ++i){
      size_t tile = (size_t)(kt * nT + nt0 + i) * 512 + lane * 8;
      short8 wh = *(const short8*)(PWH + tile);
      short8 wl = *(const short8*)(PWL + tile);
      acc[i] = __builtin_amdgcn_mfma_f32_16x16x32_bf16(ah[kt], wh, acc[i], 0, 0, 0);
      acc[i] = __builtin_amdgcn_mfma_f32_16x16x32_bf16(al[kt], wh, acc[i], 0, 0, 0);
      acc[i] = __builtin_amdgcn_mfma_f32_16x16x32_bf16(ah[kt], wl, acc[i], 0, 0, 0);
    }
  }
  int m0 = strip << 4;
  float rscale[4];
#pragma unroll
  for (int r = 0; r < 4; ++r) rscale[r] = rs ? rs[m0 + quad * 4 + r] : 1.f;
#pragma unroll
  for (int i = 0; i < 4; ++i){
    int col = (nt0 + i) * 16 + r16;
    float bv = bias ? bias[col] : 0.f;
#pragma unroll
    for (int r = 0; r < 4; ++r){
      float v = acc[i][r] * rscale[r] + bv;
      if (doRelu) v = fmaxf(v, 0.f);
      C[(size_t)(m0 + quad * 4 + r) * N + col] = v;
    }
  }
}

extern "C" void kernel_launch(void* const* d_in, const int* in_sizes, int n_in,
                              void* d_out, int out_size, void* d_ws, size_t ws_size,
                              hipStream_t stream){
  const float* x_a = (const float*)d_in[0];
  const float* x_b = (const float*)d_in[1];
  const float* W1b = (const float*)d_in[2];
  const float* b1b = (const float*)d_in[3];
  const float* W1i = (const float*)d_in[4];
  const float* b1i = (const float*)d_in[5];
  const float* W2b = (const float*)d_in[6];
  const float* b2b = (const float*)d_in[7];
  const float* W2i = (const float*)d_in[8];
  const float* b2i = (const float*)d_in[9];
  const int* bs  = (const int*)d_in[10];
  const int* bd  = (const int*)d_in[11];
  const int* isc = (const int*)d_in[12];
  const int* idt = (const int*)d_in[13];

  char* w = (char*)d_ws;
  size_t o = 0;
  auto take = [&](size_t bytes) -> void* {
    void* p = w + o; o = (o + bytes + 255) & ~(size_t)255; return p;
  };
  int* cnts = (int*)take(120000 * sizeof(int));   // c_bs[50k] c_bd[10k] c_is[10k] c_id[50k]
  int* c_bs = cnts, *c_bd = cnts + 50000, *c_is = cnts + 60000, *c_id = cnts + 70000;
  int* curs = (int*)take(60000 * sizeof(int));    // cur_bel[10k] cur_inc[50k]
  int* cur_bel = curs, *cur_inc = curs + 10000;
  int* off_bel = (int*)take((NB + 1) * sizeof(int));
  int* off_inc = (int*)take((NA + 1) * sizeof(int));
  int* csr_bel = (int*)take(NE * sizeof(int));
  int* csr_inc = (int*)take(NE * sizeof(int));
  float* s_ob = (float*)take(NA * sizeof(float));  // rsqrt deg_out bel (A)
  float* s_ib = (float*)take(NB * sizeof(float));  // rsqrt deg_in  bel (B)
  float* s_oi = (float*)take(NB * sizeof(float));  // rsqrt deg_out inc (B)
  float* s_ii = (float*)take(NA * sizeof(float));  // rsqrt deg_in  inc (A)
  u16* pwh = (u16*)take(196608 * sizeof(u16));
  u16* pwl = (u16*)take(196608 * sizeof(u16));
  u16* pwh1b = pwh, *pwh1i = pwh + 65536, *pwh2b = pwh + 131072, *pwh2i = pwh + 163840;
  u16* pwl1b = pwl, *pwl1i = pwl + 65536, *pwl2b = pwl + 131072, *pwl2i = pwl + 163840;
  float* P_b = (float*)take((size_t)NB * 256 * sizeof(float));  // also reused as P_b2
  float* G1  = (float*)take((size_t)NB * 256 * sizeof(float));  // (x_b @ W1i)*s_oi
  float* H_b = (float*)take((size_t)NB * 256 * sizeof(float));
  float* H_a = (float*)take((size_t)NA * 256 * sizeof(float));
  float* G2  = (float*)take((size_t)NB * 128 * sizeof(float));  // (H_b @ W2i)*s_oi

  float* out_a = (float*)d_out;                     // [NA,128]
  float* out_b = (float*)d_out + (size_t)NA * 128;  // [NB,128]

  // ---- graph setup (once, reused by both layers) ----
  zero_ints<<<469, 256, 0, stream>>>(cnts, 120000, curs, 60000);
  hist_kernel<<<1172, 256, 0, stream>>>(bs, bd, isc, idt, c_bs, c_bd, c_is, c_id);
  scan_kernel<<<2, 1024, 0, stream>>>(c_bd, c_id, off_bel, off_inc);
  scales_kernel<<<196, 256, 0, stream>>>(c_bs, c_bd, c_is, c_id, s_ob, s_ib, s_oi, s_ii);
  fill_kernel<<<1172, 256, 0, stream>>>(bs, bd, isc, idt, off_bel, off_inc,
                                        cur_bel, cur_inc, csr_bel, csr_inc);
  pack_kernel<<<192, 1024, 0, stream>>>(W1b, W1i, W2b, W2i, pwh, pwl);

  // ---- layer 1 ----
  // inc (B->A): transform BEFORE agg (10000 src rows << 50000 dst rows)
  gemm_kernel<<<625, 256, 0, stream>>>(x_b, pwh1i, pwl1i, nullptr, s_oi, G1, NB, 16, 2, 0);
  // bel (A->B): agg then transform
  agg_kernel<4><<<2500, 256, 0, stream>>>(x_a, s_ob, off_bel, csr_bel, P_b, NB,
                                          nullptr, nullptr, 0);
  gemm_kernel<<<625, 256, 0, stream>>>(P_b, pwh1b, pwl1b, b1b, s_ib, H_b, NB, 16, 2, 1);
  agg_kernel<4><<<12500, 256, 0, stream>>>(G1, nullptr, off_inc, csr_inc, H_a, NA,
                                           s_ii, b1i, 1);
  // ---- layer 2 ----
  gemm_kernel<<<313, 256, 0, stream>>>(H_b, pwh2i, pwl2i, nullptr, s_oi, G2, NB, 8, 1, 0);
  agg_kernel<4><<<2500, 256, 0, stream>>>(H_a, s_ob, off_bel, csr_bel, P_b, NB,
                                          nullptr, nullptr, 0);
  gemm_kernel<<<313, 256, 0, stream>>>(P_b, pwh2b, pwl2b, b2b, s_ib, out_b, NB, 8, 1, 0);
  agg_kernel<2><<<12500, 256, 0, stream>>>(G2, nullptr, off_inc, csr_inc, out_a, NA,
                                           s_ii, b2i, 0);
}

// Round 4
// 521.380 us; speedup vs baseline: 1.7316x; 1.7316x over previous
//
#include <hip/hip_runtime.h>

// RGCN bipartite, FP32 in/out. Round 4:
//   - GEMM on the 10000-row side of every relation (scales commute with W).
//   - GEMM restored to round-2 register shape (single live acc, no spills),
//     4 waves/strip over the nt range; optional bf16 store; nullable rs/bias.
//   - Aggregation gathers bf16 rows (512B / 256B): half-/quarter-wave per edge,
//     2-deep unroll => 4 gathers in flight; __shfl_xor cross-part combine;
//     fused scale+bias+relu epilogue.  Gathered tensors (xa16,G1,H_a,G2) bf16;
//     GEMM A-side tensors (x_b,P_b,H_b) stay fp32 (3-term bf16-split MFMA).
//   CSR built once, reused by both layers.

#define NA 50000
#define NB 10000
#define NE 300000

typedef unsigned short u16;
typedef unsigned int u32;
typedef __attribute__((ext_vector_type(8))) short short8;
typedef __attribute__((ext_vector_type(4))) float f32x4;

__device__ __forceinline__ float bf2f(u16 h){
  union { u32 u; float f; } x; x.u = ((u32)h) << 16; return x.f;
}
__device__ __forceinline__ u16 f2bf(float f){
  union { float f; u32 u; } x; x.f = f;
  u32 r = (x.u + 0x7FFFu + ((x.u >> 16) & 1u)) >> 16;   // RNE
  return (u16)r;
}

// ---------- zero int scratch ----------
__global__ void zero_ints(int* __restrict__ a, int na, int* __restrict__ b, int nb){
  int g = blockIdx.x * blockDim.x + threadIdx.x;
  int s = gridDim.x * blockDim.x;
  for (int i = g; i < na; i += s) a[i] = 0;
  for (int i = g; i < nb; i += s) b[i] = 0;
}

// ---------- fp32 -> bf16 convert ----------
__global__ void cvt_kernel(const float* __restrict__ X, u16* __restrict__ Y, int n){
  int g = (blockIdx.x * blockDim.x + threadIdx.x) * 4;
  int s = gridDim.x * blockDim.x * 4;
  for (int i = g; i < n; i += s){
    float4 v = *(const float4*)(X + i);
    ushort4 o; o.x = f2bf(v.x); o.y = f2bf(v.y); o.z = f2bf(v.z); o.w = f2bf(v.w);
    *(ushort4*)(Y + i) = o;
  }
}

// ---------- degree histograms ----------
__global__ void hist_kernel(const int* __restrict__ bs, const int* __restrict__ bd,
                            const int* __restrict__ isc, const int* __restrict__ idt,
                            int* __restrict__ c_bs, int* __restrict__ c_bd,
                            int* __restrict__ c_is, int* __restrict__ c_id){
  int g = blockIdx.x * blockDim.x + threadIdx.x;
  int s = gridDim.x * blockDim.x;
  for (int e = g; e < NE; e += s){
    atomicAdd(&c_bs[bs[e]], 1);
    atomicAdd(&c_bd[bd[e]], 1);
    atomicAdd(&c_is[isc[e]], 1);
    atomicAdd(&c_id[idt[e]], 1);
  }
}

// ---------- exclusive scan: block 0 -> bel offsets (NB), block 1 -> inc (NA) ----
__global__ __launch_bounds__(1024) void scan_kernel(const int* __restrict__ c_bd,
                                                    const int* __restrict__ c_id,
                                                    int* __restrict__ off_bel,
                                                    int* __restrict__ off_inc){
  const int* cnt; int* off; int n;
  if (blockIdx.x == 0){ cnt = c_bd; off = off_bel; n = NB; }
  else                { cnt = c_id; off = off_inc; n = NA; }
  __shared__ int wsum[16];
  __shared__ int carry, chunkTot;
  int tid = threadIdx.x, lane = tid & 63, wid = tid >> 6;
  if (tid == 0) carry = 0;
  __syncthreads();
  for (int base = 0; base < n; base += 4096){
    int i0 = base + tid * 4;
    int v[4];
#pragma unroll
    for (int r = 0; r < 4; ++r){ int idx = i0 + r; v[r] = (idx < n) ? cnt[idx] : 0; }
    int s = v[0] + v[1] + v[2] + v[3];
    int x = s;
#pragma unroll
    for (int d = 1; d < 64; d <<= 1){ int t = __shfl_up(x, d, 64); if (lane >= d) x += t; }
    if (lane == 63) wsum[wid] = x;
    __syncthreads();
    if (wid == 0){
      int ws = (lane < 16) ? wsum[lane] : 0;
#pragma unroll
      for (int d = 1; d < 16; d <<= 1){ int t = __shfl_up(ws, d, 64); if (lane >= d) ws += t; }
      if (lane < 16) wsum[lane] = ws;
      if (lane == 15) chunkTot = ws;
    }
    __syncthreads();
    int waveBase = (wid == 0) ? 0 : wsum[wid - 1];
    int run = carry + waveBase + (x - s);
#pragma unroll
    for (int r = 0; r < 4; ++r){ int idx = i0 + r; if (idx < n) off[idx] = run; run += v[r]; }
    __syncthreads();
    if (tid == 0) carry += chunkTot;
    __syncthreads();
  }
  if (tid == 0) off[n] = carry;
}

// ---------- rsqrt(max(deg,1)) scales ----------
__global__ void scales_kernel(const int* __restrict__ c_bs, const int* __restrict__ c_bd,
                              const int* __restrict__ c_is, const int* __restrict__ c_id,
                              float* __restrict__ s_ob, float* __restrict__ s_ib,
                              float* __restrict__ s_oi, float* __restrict__ s_ii){
  int g = blockIdx.x * blockDim.x + threadIdx.x;
  int s = gridDim.x * blockDim.x;
  for (int i = g; i < NA; i += s){
    int a = c_bs[i]; s_ob[i] = rsqrtf((float)(a > 1 ? a : 1));
    int b = c_id[i]; s_ii[i] = rsqrtf((float)(b > 1 ? b : 1));
    if (i < NB){
      int c = c_bd[i]; s_ib[i] = rsqrtf((float)(c > 1 ? c : 1));
      int d = c_is[i]; s_oi[i] = rsqrtf((float)(d > 1 ? d : 1));
    }
  }
}

// ---------- CSR fill ----------
__global__ void fill_kernel(const int* __restrict__ bs, const int* __restrict__ bd,
                            const int* __restrict__ isc, const int* __restrict__ idt,
                            const int* __restrict__ off_bel, const int* __restrict__ off_inc,
                            int* __restrict__ cur_bel, int* __restrict__ cur_inc,
                            int* __restrict__ csr_bel, int* __restrict__ csr_inc){
  int g = blockIdx.x * blockDim.x + threadIdx.x;
  int s = gridDim.x * blockDim.x;
  for (int e = g; e < NE; e += s){
    int d0 = bd[e];
    int p0 = off_bel[d0] + atomicAdd(&cur_bel[d0], 1);
    csr_bel[p0] = bs[e];
    int d1 = idt[e];
    int p1 = off_inc[d1] + atomicAdd(&cur_inc[d1], 1);
    csr_inc[p1] = isc[e];
  }
}

// ---------- pack fp32 W into MFMA B-fragment order, hi/lo bf16 split ----------
// elem index = (kt*nT + nt)*512 + lane*8 + j ; B[k=(lane>>4)*8+j][n=lane&15]
__global__ void pack_kernel(const float* __restrict__ W1b, const float* __restrict__ W1i,
                            const float* __restrict__ W2b, const float* __restrict__ W2i,
                            u16* __restrict__ pwh, u16* __restrict__ pwl){
  int g = blockIdx.x * blockDim.x + threadIdx.x;
  int s = gridDim.x * blockDim.x;
  const int total = 65536 + 65536 + 32768 + 32768;
  for (int t = g; t < total; t += s){
    const float* W; int N; int tt;
    if (t < 65536)       { W = W1b; N = 256; tt = t; }
    else if (t < 131072) { W = W1i; N = 256; tt = t - 65536; }
    else if (t < 163840) { W = W2b; N = 128; tt = t - 131072; }
    else                 { W = W2i; N = 128; tt = t - 163840; }
    int j = tt & 7, lane = (tt >> 3) & 63, tile = tt >> 9;
    int nT = N >> 4;
    int nt = tile % nT, kt = tile / nT;
    int k = kt * 32 + ((lane >> 4) << 3) + j;
    int n = nt * 16 + (lane & 15);
    float v = W[k * N + n];
    u16 hi = f2bf(v);
    pwh[t] = hi;
    pwl[t] = f2bf(v - bf2f(hi));
  }
}

// ---------- aggregation over bf16 rows ----------
// one wave per dst row; LPE = NCOL/8 lanes cover one edge's row (16B/lane),
// EPI = 64/LPE edges per iteration, 2-deep unroll => 2*EPI edges in flight.
// epilogue: r = sum * (rs?rs[row]:1) + (bias?bias[col]:0); optional relu;
// store fp32 (Pf) or bf16 (P16).
template<int NCOL, int OUTBF>
__global__ __launch_bounds__(256) void agg_kernel(const u16* __restrict__ X,
                                                  const float* __restrict__ ss,
                                                  const int* __restrict__ off,
                                                  const int* __restrict__ csr,
                                                  float* __restrict__ Pf,
                                                  u16* __restrict__ P16, int nDst,
                                                  const float* __restrict__ rs,
                                                  const float* __restrict__ bias,
                                                  int doRelu){
  const int LPE = NCOL / 8;       // 32 (NCOL=256) or 16 (NCOL=128)
  const int EPI = 64 / LPE;       // 2 or 4
  int wave = blockIdx.x * 4 + (threadIdx.x >> 6);
  int lane = threadIdx.x & 63;
  if (wave >= nDst) return;
  int b0 = off[wave], b1 = off[wave + 1];
  int part = lane / LPE;
  int cl = lane & (LPE - 1);
  int c = cl * 8;
  float a0[8], a1[8];
#pragma unroll
  for (int t = 0; t < 8; ++t){ a0[t] = 0.f; a1[t] = 0.f; }
  int j = b0;
  for (; j + 2 * EPI <= b1; j += 2 * EPI){
    int s0 = csr[j + part], s1 = csr[j + EPI + part];
    float c0 = ss ? ss[s0] : 1.f, c1 = ss ? ss[s1] : 1.f;
    short8 v0 = *(const short8*)(X + (size_t)s0 * NCOL + c);
    short8 v1 = *(const short8*)(X + (size_t)s1 * NCOL + c);
#pragma unroll
    for (int t = 0; t < 8; ++t){
      a0[t] += bf2f((u16)v0[t]) * c0;
      a1[t] += bf2f((u16)v1[t]) * c1;
    }
  }
  for (; j < b1; j += EPI){
    int e = j + part;
    if (e < b1){
      int s0 = csr[e];
      float c0 = ss ? ss[s0] : 1.f;
      short8 v0 = *(const short8*)(X + (size_t)s0 * NCOL + c);
#pragma unroll
      for (int t = 0; t < 8; ++t) a0[t] += bf2f((u16)v0[t]) * c0;
    }
  }
#pragma unroll
  for (int t = 0; t < 8; ++t) a0[t] += a1[t];
#pragma unroll
  for (int d = LPE; d < 64; d <<= 1){
#pragma unroll
    for (int t = 0; t < 8; ++t) a0[t] += __shfl_xor(a0[t], d, 64);
  }
  float rv = rs ? rs[wave] : 1.f;
#pragma unroll
  for (int t = 0; t < 8; ++t){
    float bv = bias ? bias[c + t] : 0.f;
    float v = a0[t] * rv + bv;
    if (doRelu) v = fmaxf(v, 0.f);
    a0[t] = v;
  }
  if (part == 0){
    if (OUTBF){
      short8 o;
#pragma unroll
      for (int t = 0; t < 8; ++t) o[t] = (short)f2bf(a0[t]);
      *(short8*)(P16 + (size_t)wave * NCOL + c) = o;
    } else {
      float4 f0; f0.x = a0[0]; f0.y = a0[1]; f0.z = a0[2]; f0.w = a0[3];
      float4 f1; f1.x = a0[4]; f1.y = a0[5]; f1.z = a0[6]; f1.w = a0[7];
      *(float4*)(Pf + (size_t)wave * NCOL + c) = f0;
      *(float4*)(Pf + (size_t)wave * NCOL + c + 4) = f1;
    }
  }
}

// ---------- GEMM: C[M,N] = relu?( (A[M,256] @ W) * rs[m] + bias[n] ) ----------
// fp32 via 3-term bf16 split MFMA. One wave per strip-slice: strip = 16 rows,
// (1<<wpsShift) waves per strip each covering nT>>wpsShift consecutive nt.
// SINGLE live accumulator (round-2 register shape, no spills).
__global__ __launch_bounds__(256) void gemm_kernel(const float* __restrict__ A,
                                                   const u16* __restrict__ PWH,
                                                   const u16* __restrict__ PWL,
                                                   const float* __restrict__ bias,
                                                   const float* __restrict__ rs,
                                                   float* __restrict__ Cf,
                                                   u16* __restrict__ C16,
                                                   int M, int nT, int wpsShift,
                                                   int doRelu){
  int wave = blockIdx.x * 4 + (threadIdx.x >> 6);
  int lane = threadIdx.x & 63;
  int strips = M >> 4;
  int strip = wave >> wpsShift;
  if (strip >= strips) return;
  int slice = wave & ((1 << wpsShift) - 1);
  int ntPer = nT >> wpsShift;
  int ntStart = slice * ntPer;
  int N = nT << 4;
  int r16 = lane & 15, quad = lane >> 4;
  int m0 = strip << 4;
  const float* aBase = A + (size_t)(m0 + r16) * 256 + quad * 8;
  short8 ah[8], al[8];
#pragma unroll
  for (int kt = 0; kt < 8; ++kt){
    float4 p0 = *(const float4*)(aBase + kt * 32);
    float4 p1 = *(const float4*)(aBase + kt * 32 + 4);
    float v[8] = {p0.x, p0.y, p0.z, p0.w, p1.x, p1.y, p1.z, p1.w};
    short8 h, l;
#pragma unroll
    for (int j = 0; j < 8; ++j){
      u16 hb = f2bf(v[j]);
      h[j] = (short)hb;
      l[j] = (short)f2bf(v[j] - bf2f(hb));
    }
    ah[kt] = h; al[kt] = l;
  }
  float rscale[4];
#pragma unroll
  for (int r = 0; r < 4; ++r) rscale[r] = rs ? rs[m0 + quad * 4 + r] : 1.f;
  for (int nt = ntStart; nt < ntStart + ntPer; ++nt){
    f32x4 acc = {0.f, 0.f, 0.f, 0.f};
    const u16* bh = PWH + ((size_t)nt * 64 + lane) * 8;
    const u16* bl = PWL + ((size_t)nt * 64 + lane) * 8;
#pragma unroll
    for (int kt = 0; kt < 8; ++kt){
      short8 wh = *(const short8*)(bh + (size_t)kt * nT * 512);
      short8 wl = *(const short8*)(bl + (size_t)kt * nT * 512);
      acc = __builtin_amdgcn_mfma_f32_16x16x32_bf16(ah[kt], wh, acc, 0, 0, 0);
      acc = __builtin_amdgcn_mfma_f32_16x16x32_bf16(al[kt], wh, acc, 0, 0, 0);
      acc = __builtin_amdgcn_mfma_f32_16x16x32_bf16(ah[kt], wl, acc, 0, 0, 0);
    }
    int col = nt * 16 + r16;
    float bv = bias ? bias[col] : 0.f;
#pragma unroll
    for (int r = 0; r < 4; ++r){
      float v = acc[r] * rscale[r] + bv;
      if (doRelu) v = fmaxf(v, 0.f);
      size_t idx = (size_t)(m0 + quad * 4 + r) * N + col;
      if (C16) C16[idx] = f2bf(v);
      else     Cf[idx] = v;
    }
  }
}

extern "C" void kernel_launch(void* const* d_in, const int* in_sizes, int n_in,
                              void* d_out, int out_size, void* d_ws, size_t ws_size,
                              hipStream_t stream){
  const float* x_a = (const float*)d_in[0];
  const float* x_b = (const float*)d_in[1];
  const float* W1b = (const float*)d_in[2];
  const float* b1b = (const float*)d_in[3];
  const float* W1i = (const float*)d_in[4];
  const float* b1i = (const float*)d_in[5];
  const float* W2b = (const float*)d_in[6];
  const float* b2b = (const float*)d_in[7];
  const float* W2i = (const float*)d_in[8];
  const float* b2i = (const float*)d_in[9];
  const int* bs  = (const int*)d_in[10];
  const int* bd  = (const int*)d_in[11];
  const int* isc = (const int*)d_in[12];
  const int* idt = (const int*)d_in[13];

  char* w = (char*)d_ws;
  size_t o = 0;
  auto take = [&](size_t bytes) -> void* {
    void* p = w + o; o = (o + bytes + 255) & ~(size_t)255; return p;
  };
  int* cnts = (int*)take(120000 * sizeof(int));   // c_bs[50k] c_bd[10k] c_is[10k] c_id[50k]
  int* c_bs = cnts, *c_bd = cnts + 50000, *c_is = cnts + 60000, *c_id = cnts + 70000;
  int* curs = (int*)take(60000 * sizeof(int));    // cur_bel[10k] cur_inc[50k]
  int* cur_bel = curs, *cur_inc = curs + 10000;
  int* off_bel = (int*)take((NB + 1) * sizeof(int));
  int* off_inc = (int*)take((NA + 1) * sizeof(int));
  int* csr_bel = (int*)take(NE * sizeof(int));
  int* csr_inc = (int*)take(NE * sizeof(int));
  float* s_ob = (float*)take(NA * sizeof(float));  // rsqrt deg_out bel (A)
  float* s_ib = (float*)take(NB * sizeof(float));  // rsqrt deg_in  bel (B)
  float* s_oi = (float*)take(NB * sizeof(float));  // rsqrt deg_out inc (B)
  float* s_ii = (float*)take(NA * sizeof(float));  // rsqrt deg_in  inc (A)
  u16* pwh = (u16*)take(196608 * sizeof(u16));
  u16* pwl = (u16*)take(196608 * sizeof(u16));
  u16* pwh1b = pwh, *pwh1i = pwh + 65536, *pwh2b = pwh + 131072, *pwh2i = pwh + 163840;
  u16* pwl1b = pwl, *pwl1i = pwl + 65536, *pwl2b = pwl + 131072, *pwl2i = pwl + 163840;
  u16* xa16 = (u16*)take((size_t)NA * 256 * sizeof(u16));   // x_a in bf16 (gathered)
  u16* G1   = (u16*)take((size_t)NB * 256 * sizeof(u16));   // (x_b@W1i)*s_oi, bf16
  u16* H_a  = (u16*)take((size_t)NA * 256 * sizeof(u16));   // layer-1 A feats, bf16
  u16* G2   = (u16*)take((size_t)NB * 128 * sizeof(u16));   // (H_b@W2i)*s_oi, bf16
  float* P_b = (float*)take((size_t)NB * 256 * sizeof(float)); // agg out (fp32), reused L2
  float* H_b = (float*)take((size_t)NB * 256 * sizeof(float)); // layer-1 B feats, fp32

  float* out_a = (float*)d_out;                     // [NA,128]
  float* out_b = (float*)d_out + (size_t)NA * 128;  // [NB,128]

  // ---- graph setup (once, reused by both layers) ----
  zero_ints<<<469, 256, 0, stream>>>(cnts, 120000, curs, 60000);
  hist_kernel<<<1172, 256, 0, stream>>>(bs, bd, isc, idt, c_bs, c_bd, c_is, c_id);
  scan_kernel<<<2, 1024, 0, stream>>>(c_bd, c_id, off_bel, off_inc);
  scales_kernel<<<196, 256, 0, stream>>>(c_bs, c_bd, c_is, c_id, s_ob, s_ib, s_oi, s_ii);
  fill_kernel<<<1172, 256, 0, stream>>>(bs, bd, isc, idt, off_bel, off_inc,
                                        cur_bel, cur_inc, csr_bel, csr_inc);
  pack_kernel<<<192, 1024, 0, stream>>>(W1b, W1i, W2b, W2i, pwh, pwl);
  cvt_kernel<<<1024, 256, 0, stream>>>(x_a, xa16, NA * 256);

  // ---- layer 1 ----
  // inc (B->A): transform 10000 rows BEFORE aggregating; fold s_oi; bf16 out
  gemm_kernel<<<625, 256, 0, stream>>>(x_b, pwh1i, pwl1i, nullptr, s_oi,
                                       nullptr, G1, NB, 16, 2, 0);
  // bel (A->B): aggregate bf16 x_a, fp32 out; then transform
  agg_kernel<256, 0><<<2500, 256, 0, stream>>>(xa16, s_ob, off_bel, csr_bel,
                                               P_b, nullptr, NB, nullptr, nullptr, 0);
  gemm_kernel<<<625, 256, 0, stream>>>(P_b, pwh1b, pwl1b, b1b, s_ib,
                                       H_b, nullptr, NB, 16, 2, 1);
  agg_kernel<256, 1><<<12500, 256, 0, stream>>>(G1, nullptr, off_inc, csr_inc,
                                                nullptr, H_a, NA, s_ii, b1i, 1);
  // ---- layer 2 ----
  gemm_kernel<<<625, 256, 0, stream>>>(H_b, pwh2i, pwl2i, nullptr, s_oi,
                                       nullptr, G2, NB, 8, 2, 0);
  agg_kernel<256, 0><<<2500, 256, 0, stream>>>(H_a, s_ob, off_bel, csr_bel,
                                               P_b, nullptr, NB, nullptr, nullptr, 0);
  gemm_kernel<<<625, 256, 0, stream>>>(P_b, pwh2b, pwl2b, b2b, s_ib,
                                       out_b, nullptr, NB, 8, 2, 0);
  agg_kernel<128, 0><<<12500, 256, 0, stream>>>(G2, nullptr, off_inc, csr_inc,
                                                out_a, nullptr, NA, s_ii, b2i, 0);
}